// Round 11
// baseline (516.022 us; speedup 1.0000x reference)
//
#include <hip/hip_runtime.h>
#include <math.h>

#define B_   32
#define L_   256
#define S_   64
#define D_   128
#define NTOK (B_*L_)   // 8192

// ---------------------------------------------------------------------------
// ONE fused kernel. 4 tokens/block (same b), 256 threads, 2048 blocks.
// R10 PMC: 216us, HBM 4%, VALUBusy 22% -> latency-bound in the per-row
// online-softmax serial chain (4 shuffles + 3 exp + rescale per 2 rows).
// R11 change: lane-per-station scores. Lane i streams row lst[i] (512B own
// stream), qk via LDS *broadcast* reads -> 4 head dots with NO cross-lane ops
// and NO serial rescale. Softmax = ONE 64-lane butterfly per token (x4 heads,
// ILP). Then normalized w -> LDS (float4 per station), u-accum = coalesced
// dependency-free FMA loop over just-streamed (L1/L2-hot) rows.
// LDS regions (floats), reused across phases (19.4 KB, 8 blocks/CU):
//   X  [4*132]  x tokens (live whole kernel)
//   QK [4*528]  per-token: qk fragments -> sc overlay (wave-private) ->
//               ctx[tok*132+d] @0..523 -> y @528..1051
//   A  [4*528]  q (first 524) -> u[tok][h*132+d] -> o[tok*132+d]
// ---------------------------------------------------------------------------
__global__ __launch_bounds__(256) void fused_kernel(
        const float* __restrict__ h_wq,  const float* __restrict__ h_all,
        const int* __restrict__ station_id, const float* __restrict__ adj,
        const float* __restrict__ in_proj_w, const float* __restrict__ in_proj_b,
        const float* __restrict__ out_w,  const float* __restrict__ out_b,
        const float* __restrict__ gate_w, const float* __restrict__ gate_b,
        const float* __restrict__ ln_g,   const float* __restrict__ ln_b,
        const float* __restrict__ alpha,  float* __restrict__ out) {
    __shared__ float X[4*132];
    __shared__ float QK[4*528];
    __shared__ float A[4*528];
    __shared__ float cb[4][4];
    __shared__ int   lst[64];
    __shared__ int   cnt_s;

    const int t0  = blockIdx.x * 4;   // 4 tokens, same b (4 | 256)
    const int b   = t0 >> 8;
    const int tid = threadIdx.x;
    const int wv  = tid >> 6, lane = tid & 63;
    const int d   = tid & 127, pr = tid >> 7;
    const int tA  = 2*pr, tB = 2*pr + 1;
    const float scale = 0.17677669529663687f;     // 1/sqrt(32)

    // ---- P0: mask ballot (wave 0) + x staging (threads 0..127)
    if (tid < 64) {
        int sid = station_id[b];
        int s = tid;
        bool av = (adj[sid*S_ + s] > 0.0f) && (s != sid);
        unsigned long long m = __ballot(av);
        if (m == 0ull) { av = (s != sid); m = __ballot(av); }   // all-but-self
        if (m == 0ull) { av = (s == sid); m = __ballot(av); }   // S==1 safety
        int idx = __popcll(m & ((1ull << s) - 1ull));
        if (av) lst[idx] = s;
        if (s == 0) cnt_s = __popcll(m);
    }
    if (tid < 128) {
        int tok = tid >> 5, d4 = tid & 31;
        *(float4*)&X[tok*132 + d4*4] =
            *(const float4*)(h_wq + (size_t)(t0 + tok)*128 + d4*4);
    }
    __syncthreads();

    // ---- P1: q[tok][d] = qb[d] + qw[d,:].x[tok]   (2 tokens per thread)
    {
        const float4* wrow = (const float4*)(in_proj_w + (size_t)d*128);
        const float qb = in_proj_b[d];
        float a0 = qb, a1 = qb;
        const float* x0 = &X[tA*132];
        const float* x1 = &X[tB*132];
        #pragma unroll 8
        for (int j4 = 0; j4 < 32; ++j4) {
            float4 w  = wrow[j4];
            float4 u0 = *(const float4*)(x0 + j4*4);
            float4 u1 = *(const float4*)(x1 + j4*4);
            a0 += w.x*u0.x + w.y*u0.y + w.z*u0.z + w.w*u0.w;
            a1 += w.x*u1.x + w.y*u1.y + w.z*u1.z + w.w*u1.w;
        }
        A[tA*132 + d] = a0;
        A[tB*132 + d] = a1;
    }
    __syncthreads();

    // ---- P2: qk[tok][h][d] = scale * sum_j kw[h*32+j, d] * q[tok][h*32+j]
    {
        const float* q0 = &A[tA*132];
        const float* q1 = &A[tB*132];
        #pragma unroll
        for (int h = 0; h < 4; ++h) {
            float a0 = 0.f, a1 = 0.f;
            const float* wcol = in_proj_w + (size_t)(128 + h*32)*128 + d;
            #pragma unroll 8
            for (int j = 0; j < 32; ++j) {
                float w = wcol[(size_t)j*128];   // coalesced across d-lanes
                a0 += w * q0[h*32 + j];
                a1 += w * q1[h*32 + j];
            }
            QK[tA*528 + h*132 + d] = a0 * scale;
            QK[tB*528 + h*132 + d] = a1 * scale;
        }
    }
    if (tid < 16) {
        int tok = tid >> 2, h = tid & 3;
        float s = 0.f;
        for (int j = 0; j < 32; ++j)
            s += A[tok*132 + h*32 + j] * in_proj_b[128 + h*32 + j];
        cb[tok][h] = s * scale;
    }
    __syncthreads();

    // ---- P3: attention, lane-per-station. Wave wv owns token t0+wv.
    {
        const int cnt = cnt_s;
        const int ridx = lst[lane < cnt ? lane : 0];
        const float* rp  = h_all + (size_t)(t0 + wv)*(S_*D_) + (size_t)ridx*D_;
        const float* qkb = &QK[wv*528];

        // scores: lane streams its own row; qk via LDS broadcast (free)
        float s0 = cb[wv][0], s1 = cb[wv][1], s2 = cb[wv][2], s3 = cb[wv][3];
        #pragma unroll 8
        for (int j4 = 0; j4 < 32; ++j4) {
            float4 x  = *(const float4*)(rp + j4*4);
            float4 w0 = *(const float4*)(qkb + 0*132 + j4*4);
            float4 w1 = *(const float4*)(qkb + 1*132 + j4*4);
            float4 w2 = *(const float4*)(qkb + 2*132 + j4*4);
            float4 w3 = *(const float4*)(qkb + 3*132 + j4*4);
            s0 += w0.x*x.x + w0.y*x.y + w0.z*x.z + w0.w*x.w;
            s1 += w1.x*x.x + w1.y*x.y + w1.z*x.z + w1.w*x.w;
            s2 += w2.x*x.x + w2.y*x.y + w2.z*x.z + w2.w*x.w;
            s3 += w3.x*x.x + w3.y*x.y + w3.z*x.z + w3.w*x.w;
        }
        const bool act = (lane < cnt);
        if (!act) { s0 = s1 = s2 = s3 = -INFINITY; }

        // softmax across lanes, once per token (4 heads in parallel)
        float m0 = s0, m1 = s1, m2 = s2, m3 = s3;
        #pragma unroll
        for (int o = 32; o >= 1; o >>= 1) {
            m0 = fmaxf(m0, __shfl_xor(m0, o));
            m1 = fmaxf(m1, __shfl_xor(m1, o));
            m2 = fmaxf(m2, __shfl_xor(m2, o));
            m3 = fmaxf(m3, __shfl_xor(m3, o));
        }
        float p0 = act ? __expf(s0 - m0) : 0.f;
        float p1 = act ? __expf(s1 - m1) : 0.f;
        float p2 = act ? __expf(s2 - m2) : 0.f;
        float p3 = act ? __expf(s3 - m3) : 0.f;
        float q0 = p0, q1 = p1, q2 = p2, q3 = p3;
        #pragma unroll
        for (int o = 32; o >= 1; o >>= 1) {
            q0 += __shfl_xor(q0, o);
            q1 += __shfl_xor(q1, o);
            q2 += __shfl_xor(q2, o);
            q3 += __shfl_xor(q3, o);
        }
        float4 wv4;
        wv4.x = p0 / q0; wv4.y = p1 / q1; wv4.z = p2 / q2; wv4.w = p3 / q3;
        // overlay normalized w into this wave's (dead) qk region: [i*4 + h]
        *(float4*)&QK[wv*528 + lane*4] = wv4;   // wave-private, no barrier

        // u-accum: coalesced, dependency-free (rows L1/L2-hot)
        float u00=0,u01=0,u10=0,u11=0,u20=0,u21=0,u30=0,u31=0;
        const float* base = h_all + (size_t)(t0 + wv)*(S_*D_);
        for (int i = 0; i < cnt; ++i) {
            const float* rb = base + (size_t)lst[i]*D_;
            float x0 = rb[lane], x1 = rb[64 + lane];
            float4 w = *(const float4*)&QK[wv*528 + i*4];   // broadcast
            u00 += w.x*x0; u01 += w.x*x1;
            u10 += w.y*x0; u11 += w.y*x1;
            u20 += w.z*x0; u21 += w.z*x1;
            u30 += w.w*x0; u31 += w.w*x1;
        }
        A[wv*528 + 0*132 + lane] = u00;  A[wv*528 + 0*132 + 64 + lane] = u01;
        A[wv*528 + 1*132 + lane] = u10;  A[wv*528 + 1*132 + 64 + lane] = u11;
        A[wv*528 + 2*132 + lane] = u20;  A[wv*528 + 2*132 + 64 + lane] = u21;
        A[wv*528 + 3*132 + lane] = u30;  A[wv*528 + 3*132 + 64 + lane] = u31;
    }
    __syncthreads();

    // ---- P4: ctx[tok][d] = vb[d] + vw[d,:].u[tok][h(d)]  -> QK[tok*132+d]
    {
        const int h = d >> 5;
        const float4* vwrow = (const float4*)(in_proj_w + (size_t)(256 + d)*128);
        const float vb = in_proj_b[256 + d];
        float a0 = vb, a1 = vb;
        const float* u0 = &A[tA*528 + h*132];
        const float* u1 = &A[tB*528 + h*132];
        #pragma unroll 8
        for (int j4 = 0; j4 < 32; ++j4) {
            float4 w  = vwrow[j4];
            float4 v0 = *(const float4*)(u0 + j4*4);
            float4 v1 = *(const float4*)(u1 + j4*4);
            a0 += w.x*v0.x + w.y*v0.y + w.z*v0.z + w.w*v0.w;
            a1 += w.x*v1.x + w.y*v1.y + w.z*v1.z + w.w*v1.w;
        }
        QK[tA*132 + d] = a0;     // overwrites wave0's dead sc/qk region
        QK[tB*132 + d] = a1;
    }
    __syncthreads();

    // ---- P5: o[tok][d] = ob[d] + ow[d,:].ctx[tok]  -> A[tok*132+d]
    {
        const float4* wrow = (const float4*)(out_w + (size_t)d*128);
        const float ob = out_b[d];
        float a0 = ob, a1 = ob;
        const float* c0 = &QK[tA*132];
        const float* c1 = &QK[tB*132];
        #pragma unroll 8
        for (int j4 = 0; j4 < 32; ++j4) {
            float4 w  = wrow[j4];
            float4 v0 = *(const float4*)(c0 + j4*4);
            float4 v1 = *(const float4*)(c1 + j4*4);
            a0 += w.x*v0.x + w.y*v0.y + w.z*v0.z + w.w*v0.w;
            a1 += w.x*v1.x + w.y*v1.y + w.z*v1.z + w.w*v1.w;
        }
        __syncthreads();   // all u reads done; A reusable
        A[tA*132 + d] = a0;
        A[tB*132 + d] = a1;
    }
    __syncthreads();

    // ---- P6: gate + residual -> y into QK[528 + tok*132 + d]
    {
        const float4* wrow = (const float4*)(gate_w + (size_t)d*256);
        const float gb = gate_b[d];
        float g0 = gb, g1 = gb;
        const float* x0 = &X[tA*132];
        const float* x1 = &X[tB*132];
        const float* o0 = &A[tA*132];
        const float* o1 = &A[tB*132];
        #pragma unroll 4
        for (int j4 = 0; j4 < 32; ++j4) {
            float4 wx = wrow[j4];
            float4 wo = wrow[32 + j4];
            float4 vx0 = *(const float4*)(x0 + j4*4);
            float4 vx1 = *(const float4*)(x1 + j4*4);
            float4 vo0 = *(const float4*)(o0 + j4*4);
            float4 vo1 = *(const float4*)(o1 + j4*4);
            g0 += wx.x*vx0.x + wx.y*vx0.y + wx.z*vx0.z + wx.w*vx0.w
                + wo.x*vo0.x + wo.y*vo0.y + wo.z*vo0.z + wo.w*vo0.w;
            g1 += wx.x*vx1.x + wx.y*vx1.y + wx.z*vx1.z + wx.w*vx1.w
                + wo.x*vo1.x + wo.y*vo1.y + wo.z*vo1.z + wo.w*vo1.w;
        }
        const float al = alpha[0];
        float s0 = 1.0f / (1.0f + __expf(-g0));
        float s1 = 1.0f / (1.0f + __expf(-g1));
        QK[528 + tA*132 + d] = x0[d] + al * s0 * o0[d];
        QK[528 + tB*132 + d] = x1[d] + al * s1 * o1[d];
    }
    __syncthreads();

    // ---- P7: LayerNorm, wave wv owns token wv (dims lane, lane+64)
    {
        float y0 = QK[528 + wv*132 + lane];
        float y1 = QK[528 + wv*132 + 64 + lane];
        float s = y0 + y1;
        #pragma unroll
        for (int o = 32; o >= 1; o >>= 1) s += __shfl_xor(s, o);
        float mu = s * (1.0f/128.0f);
        float d0 = y0 - mu, d1 = y1 - mu;
        float v = d0*d0 + d1*d1;
        #pragma unroll
        for (int o = 32; o >= 1; o >>= 1) v += __shfl_xor(v, o);
        float rs = rsqrtf(v*(1.0f/128.0f) + 1e-5f);
        out[(size_t)(t0 + wv)*128 + lane]      = d0*rs*ln_g[lane]    + ln_b[lane];
        out[(size_t)(t0 + wv)*128 + 64 + lane] = d1*rs*ln_g[64+lane] + ln_b[64+lane];
    }
}

// ---------------------------------------------------------------------------
extern "C" void kernel_launch(void* const* d_in, const int* in_sizes, int n_in,
                              void* d_out, int out_size, void* d_ws, size_t ws_size,
                              hipStream_t stream) {
    const float* h_wq       = (const float*)d_in[0];
    const float* h_all      = (const float*)d_in[1];
    const int*   station_id = (const int*)  d_in[2];
    const float* adj        = (const float*)d_in[3];
    const float* in_proj_w  = (const float*)d_in[4];
    const float* in_proj_b  = (const float*)d_in[5];
    const float* out_w      = (const float*)d_in[6];
    const float* out_b      = (const float*)d_in[7];
    const float* gate_w     = (const float*)d_in[8];
    const float* gate_b     = (const float*)d_in[9];
    const float* ln_g       = (const float*)d_in[10];
    const float* ln_b       = (const float*)d_in[11];
    const float* alpha      = (const float*)d_in[12];
    float* out = (float*)d_out;

    fused_kernel<<<NTOK/4, 256, 0, stream>>>(
        h_wq, h_all, station_id, adj, in_proj_w, in_proj_b,
        out_w, out_b, gate_w, gate_b, ln_g, ln_b, alpha, out);
}

// Round 12
// 440.385 us; speedup vs baseline: 1.1718x; 1.1718x over previous
//
#include <hip/hip_runtime.h>
#include <math.h>

#define B_   32
#define L_   256
#define S_   64
#define D_   128
#define NTOK (B_*L_)   // 8192
#define TPB  8         // tokens per block

// ---------------------------------------------------------------------------
// ONE fused kernel. 8 tokens/block (same b), 256 threads, 1024 blocks.
// R11 PMC: 231us, HBM 5.5%, VALUBusy 21%, Occ 31% -> latency-bound in ALL
// matvec phases: per-lane stride-512B weight rows (64 lines/load) from L1/L2
// amortized over only 4 tokens, with ~3 blocks/CU of TLP.
// R12: 4 tokens per THREAD (acc[4], 16 FMA per weight load), 38KB LDS ->
// 4 independent blocks/CU (16 waves/CU, independent barrier groups).
// LDS regions (floats), reused:
//   X [8*132] x tokens (live whole kernel)
//   QK[8*528] qk fragments -> sc overlay (wave-private) -> ctx[tok*132+d]
//             @[0,1056) -> y @[1056,2112)
//   A [8*528] q (first 1056) -> u[tok][h*132+d] -> o[tok*132+d]
// ---------------------------------------------------------------------------
__global__ __launch_bounds__(256) void fused_kernel(
        const float* __restrict__ h_wq,  const float* __restrict__ h_all,
        const int* __restrict__ station_id, const float* __restrict__ adj,
        const float* __restrict__ in_proj_w, const float* __restrict__ in_proj_b,
        const float* __restrict__ out_w,  const float* __restrict__ out_b,
        const float* __restrict__ gate_w, const float* __restrict__ gate_b,
        const float* __restrict__ ln_g,   const float* __restrict__ ln_b,
        const float* __restrict__ alpha,  float* __restrict__ out) {
    __shared__ float X[TPB*132];
    __shared__ float QK[TPB*528];
    __shared__ float A[TPB*528];
    __shared__ float cb[TPB][4];
    __shared__ int   lst[64];
    __shared__ int   cnt_s;

    const int t0  = blockIdx.x * TPB;   // 8 tokens, same b (8 | 256)
    const int b   = t0 >> 8;
    const int tid = threadIdx.x;
    const int wv  = tid >> 6, lane = tid & 63;
    const int d   = tid & 127, pr = tid >> 7;     // pr uniform per wave
    const int tb  = 4*pr;                          // this thread's 4 tokens
    const float scale = 0.17677669529663687f;      // 1/sqrt(32)

    // ---- P0: mask ballot (wave 0) + x staging (all 256 threads)
    if (tid < 64) {
        int sid = station_id[b];
        int s = tid;
        bool av = (adj[sid*S_ + s] > 0.0f) && (s != sid);
        unsigned long long m = __ballot(av);
        if (m == 0ull) { av = (s != sid); m = __ballot(av); }   // all-but-self
        if (m == 0ull) { av = (s == sid); m = __ballot(av); }   // S==1 safety
        int idx = __popcll(m & ((1ull << s) - 1ull));
        if (av) lst[idx] = s;
        if (s == 0) cnt_s = __popcll(m);
    }
    {   // 8 tokens x 32 float4 = 256
        int tok = tid >> 5, d4 = tid & 31;
        *(float4*)&X[tok*132 + d4*4] =
            *(const float4*)(h_wq + (size_t)(t0 + tok)*128 + d4*4);
    }
    __syncthreads();

    // ---- P1: q[tok][d] = qb[d] + qw[d,:].x[tok]   (4 tokens per thread)
    {
        const float4* wrow = (const float4*)(in_proj_w + (size_t)d*128);
        const float qb = in_proj_b[d];
        float a0 = qb, a1 = qb, a2 = qb, a3 = qb;
        const float *x0 = &X[(tb+0)*132], *x1 = &X[(tb+1)*132];
        const float *x2 = &X[(tb+2)*132], *x3 = &X[(tb+3)*132];
        #pragma unroll 8
        for (int j4 = 0; j4 < 32; ++j4) {
            float4 w  = wrow[j4];
            float4 u0 = *(const float4*)(x0 + j4*4);
            float4 u1 = *(const float4*)(x1 + j4*4);
            float4 u2 = *(const float4*)(x2 + j4*4);
            float4 u3 = *(const float4*)(x3 + j4*4);
            a0 += w.x*u0.x + w.y*u0.y + w.z*u0.z + w.w*u0.w;
            a1 += w.x*u1.x + w.y*u1.y + w.z*u1.z + w.w*u1.w;
            a2 += w.x*u2.x + w.y*u2.y + w.z*u2.z + w.w*u2.w;
            a3 += w.x*u3.x + w.y*u3.y + w.z*u3.z + w.w*u3.w;
        }
        A[(tb+0)*132 + d] = a0;  A[(tb+1)*132 + d] = a1;
        A[(tb+2)*132 + d] = a2;  A[(tb+3)*132 + d] = a3;
    }
    __syncthreads();

    // ---- P2: qk[tok][h][d] = scale * sum_j kw[h*32+j, d] * q[tok][h*32+j]
    {
        #pragma unroll
        for (int h = 0; h < 4; ++h) {
            float a0 = 0.f, a1 = 0.f, a2 = 0.f, a3 = 0.f;
            const float* wcol = in_proj_w + (size_t)(128 + h*32)*128 + d;
            #pragma unroll 8
            for (int j = 0; j < 32; ++j) {
                float w = wcol[(size_t)j*128];   // coalesced across d-lanes
                a0 += w * A[(tb+0)*132 + h*32 + j];
                a1 += w * A[(tb+1)*132 + h*32 + j];
                a2 += w * A[(tb+2)*132 + h*32 + j];
                a3 += w * A[(tb+3)*132 + h*32 + j];
            }
            QK[(tb+0)*528 + h*132 + d] = a0 * scale;
            QK[(tb+1)*528 + h*132 + d] = a1 * scale;
            QK[(tb+2)*528 + h*132 + d] = a2 * scale;
            QK[(tb+3)*528 + h*132 + d] = a3 * scale;
        }
    }
    if (tid < 32) {   // cb for 8 tokens x 4 heads
        int tok = tid >> 2, h = tid & 3;
        float s = 0.f;
        for (int j = 0; j < 32; ++j)
            s += A[tok*132 + h*32 + j] * in_proj_b[128 + h*32 + j];
        cb[tok][h] = s * scale;
    }
    __syncthreads();

    // ---- P3: attention, lane-per-station; wave wv owns tokens 2wv, 2wv+1
    {
        const int cnt = cnt_s;
        #pragma unroll
        for (int k = 0; k < 2; ++k) {
            const int tl = 2*wv + k;
            const int ridx = lst[lane < cnt ? lane : 0];
            const float* base = h_all + (size_t)(t0 + tl)*(S_*D_);
            const float* rp = base + (size_t)ridx*D_;
            const float* qkb = &QK[tl*528];

            float s0 = cb[tl][0], s1 = cb[tl][1], s2 = cb[tl][2], s3 = cb[tl][3];
            #pragma unroll 8
            for (int j4 = 0; j4 < 32; ++j4) {
                float4 x  = *(const float4*)(rp + j4*4);
                float4 w0 = *(const float4*)(qkb + 0*132 + j4*4);
                float4 w1 = *(const float4*)(qkb + 1*132 + j4*4);
                float4 w2 = *(const float4*)(qkb + 2*132 + j4*4);
                float4 w3 = *(const float4*)(qkb + 3*132 + j4*4);
                s0 += w0.x*x.x + w0.y*x.y + w0.z*x.z + w0.w*x.w;
                s1 += w1.x*x.x + w1.y*x.y + w1.z*x.z + w1.w*x.w;
                s2 += w2.x*x.x + w2.y*x.y + w2.z*x.z + w2.w*x.w;
                s3 += w3.x*x.x + w3.y*x.y + w3.z*x.z + w3.w*x.w;
            }
            const bool act = (lane < cnt);
            if (!act) { s0 = s1 = s2 = s3 = -INFINITY; }

            float m0 = s0, m1 = s1, m2 = s2, m3 = s3;
            #pragma unroll
            for (int o = 32; o >= 1; o >>= 1) {
                m0 = fmaxf(m0, __shfl_xor(m0, o));
                m1 = fmaxf(m1, __shfl_xor(m1, o));
                m2 = fmaxf(m2, __shfl_xor(m2, o));
                m3 = fmaxf(m3, __shfl_xor(m3, o));
            }
            float p0 = act ? __expf(s0 - m0) : 0.f;
            float p1 = act ? __expf(s1 - m1) : 0.f;
            float p2 = act ? __expf(s2 - m2) : 0.f;
            float p3 = act ? __expf(s3 - m3) : 0.f;
            float q0 = p0, q1 = p1, q2 = p2, q3 = p3;
            #pragma unroll
            for (int o = 32; o >= 1; o >>= 1) {
                q0 += __shfl_xor(q0, o);
                q1 += __shfl_xor(q1, o);
                q2 += __shfl_xor(q2, o);
                q3 += __shfl_xor(q3, o);
            }
            float4 wv4;
            wv4.x = p0 / q0; wv4.y = p1 / q1; wv4.z = p2 / q2; wv4.w = p3 / q3;
            *(float4*)&QK[tl*528 + lane*4] = wv4;   // wave-private overlay

            // u-accum: one coalesced float2 load per row (L1/L2-hot)
            float2 u0 = {0,0}, u1 = {0,0}, u2 = {0,0}, u3 = {0,0};
            for (int i = 0; i < cnt; ++i) {
                float2 x = *(const float2*)(base + (size_t)lst[i]*D_ + 2*lane);
                float4 w = *(const float4*)&QK[tl*528 + i*4];   // broadcast
                u0.x += w.x*x.x; u0.y += w.x*x.y;
                u1.x += w.y*x.x; u1.y += w.y*x.y;
                u2.x += w.z*x.x; u2.y += w.z*x.y;
                u3.x += w.w*x.x; u3.y += w.w*x.y;
            }
            *(float2*)&A[tl*528 + 0*132 + 2*lane] = u0;
            *(float2*)&A[tl*528 + 1*132 + 2*lane] = u1;
            *(float2*)&A[tl*528 + 2*132 + 2*lane] = u2;
            *(float2*)&A[tl*528 + 3*132 + 2*lane] = u3;
        }
    }
    __syncthreads();

    // ---- P4: ctx[tok][d] = vb[d] + vw[d,:].u[tok][h(d)]  -> QK[tok*132+d]
    {
        const int h = d >> 5;
        const float4* vwrow = (const float4*)(in_proj_w + (size_t)(256 + d)*128);
        const float vb = in_proj_b[256 + d];
        float a0 = vb, a1 = vb, a2 = vb, a3 = vb;
        const float *u0 = &A[(tb+0)*528 + h*132], *u1 = &A[(tb+1)*528 + h*132];
        const float *u2 = &A[(tb+2)*528 + h*132], *u3 = &A[(tb+3)*528 + h*132];
        #pragma unroll 8
        for (int j4 = 0; j4 < 32; ++j4) {
            float4 w  = vwrow[j4];
            float4 v0 = *(const float4*)(u0 + j4*4);
            float4 v1 = *(const float4*)(u1 + j4*4);
            float4 v2 = *(const float4*)(u2 + j4*4);
            float4 v3 = *(const float4*)(u3 + j4*4);
            a0 += w.x*v0.x + w.y*v0.y + w.z*v0.z + w.w*v0.w;
            a1 += w.x*v1.x + w.y*v1.y + w.z*v1.z + w.w*v1.w;
            a2 += w.x*v2.x + w.y*v2.y + w.z*v2.z + w.w*v2.w;
            a3 += w.x*v3.x + w.y*v3.y + w.z*v3.z + w.w*v3.w;
        }
        QK[(tb+0)*132 + d] = a0;  QK[(tb+1)*132 + d] = a1;   // over dead qk/sc
        QK[(tb+2)*132 + d] = a2;  QK[(tb+3)*132 + d] = a3;
    }
    __syncthreads();

    // ---- P5: o[tok][d] = ob[d] + ow[d,:].ctx[tok]  -> A[tok*132+d]
    {
        const float4* wrow = (const float4*)(out_w + (size_t)d*128);
        const float ob = out_b[d];
        float a0 = ob, a1 = ob, a2 = ob, a3 = ob;
        const float *c0 = &QK[(tb+0)*132], *c1 = &QK[(tb+1)*132];
        const float *c2 = &QK[(tb+2)*132], *c3 = &QK[(tb+3)*132];
        #pragma unroll 8
        for (int j4 = 0; j4 < 32; ++j4) {
            float4 w  = wrow[j4];
            float4 v0 = *(const float4*)(c0 + j4*4);
            float4 v1 = *(const float4*)(c1 + j4*4);
            float4 v2 = *(const float4*)(c2 + j4*4);
            float4 v3 = *(const float4*)(c3 + j4*4);
            a0 += w.x*v0.x + w.y*v0.y + w.z*v0.z + w.w*v0.w;
            a1 += w.x*v1.x + w.y*v1.y + w.z*v1.z + w.w*v1.w;
            a2 += w.x*v2.x + w.y*v2.y + w.z*v2.z + w.w*v2.w;
            a3 += w.x*v3.x + w.y*v3.y + w.z*v3.z + w.w*v3.w;
        }
        __syncthreads();   // u reads done; A reusable
        A[(tb+0)*132 + d] = a0;  A[(tb+1)*132 + d] = a1;
        A[(tb+2)*132 + d] = a2;  A[(tb+3)*132 + d] = a3;
    }
    __syncthreads();

    // ---- P6: gate + residual -> y into QK[1056 + tok*132 + d]
    {
        const float4* wrow = (const float4*)(gate_w + (size_t)d*256);
        const float gb = gate_b[d];
        float g0 = gb, g1 = gb, g2 = gb, g3 = gb;
        const float *x0 = &X[(tb+0)*132], *x1 = &X[(tb+1)*132];
        const float *x2 = &X[(tb+2)*132], *x3 = &X[(tb+3)*132];
        const float *o0 = &A[(tb+0)*132], *o1 = &A[(tb+1)*132];
        const float *o2 = &A[(tb+2)*132], *o3 = &A[(tb+3)*132];
        #pragma unroll 4
        for (int j4 = 0; j4 < 32; ++j4) {
            float4 wx = wrow[j4];
            float4 wo = wrow[32 + j4];
            float4 a, o;
            a = *(const float4*)(x0 + j4*4); o = *(const float4*)(o0 + j4*4);
            g0 += wx.x*a.x + wx.y*a.y + wx.z*a.z + wx.w*a.w
                + wo.x*o.x + wo.y*o.y + wo.z*o.z + wo.w*o.w;
            a = *(const float4*)(x1 + j4*4); o = *(const float4*)(o1 + j4*4);
            g1 += wx.x*a.x + wx.y*a.y + wx.z*a.z + wx.w*a.w
                + wo.x*o.x + wo.y*o.y + wo.z*o.z + wo.w*o.w;
            a = *(const float4*)(x2 + j4*4); o = *(const float4*)(o2 + j4*4);
            g2 += wx.x*a.x + wx.y*a.y + wx.z*a.z + wx.w*a.w
                + wo.x*o.x + wo.y*o.y + wo.z*o.z + wo.w*o.w;
            a = *(const float4*)(x3 + j4*4); o = *(const float4*)(o3 + j4*4);
            g3 += wx.x*a.x + wx.y*a.y + wx.z*a.z + wx.w*a.w
                + wo.x*o.x + wo.y*o.y + wo.z*o.z + wo.w*o.w;
        }
        const float al = alpha[0];
        float s0 = 1.0f/(1.0f + __expf(-g0)), s1 = 1.0f/(1.0f + __expf(-g1));
        float s2 = 1.0f/(1.0f + __expf(-g2)), s3 = 1.0f/(1.0f + __expf(-g3));
        QK[1056 + (tb+0)*132 + d] = x0[d] + al*s0*o0[d];
        QK[1056 + (tb+1)*132 + d] = x1[d] + al*s1*o1[d];
        QK[1056 + (tb+2)*132 + d] = x2[d] + al*s2*o2[d];
        QK[1056 + (tb+3)*132 + d] = x3[d] + al*s3*o3[d];
    }
    __syncthreads();

    // ---- P7: LayerNorm; wave wv owns tokens 2wv, 2wv+1
    {
        #pragma unroll
        for (int k = 0; k < 2; ++k) {
            const int tl = 2*wv + k;
            float y0 = QK[1056 + tl*132 + lane];
            float y1 = QK[1056 + tl*132 + 64 + lane];
            float s = y0 + y1;
            #pragma unroll
            for (int o = 32; o >= 1; o >>= 1) s += __shfl_xor(s, o);
            float mu = s * (1.0f/128.0f);
            float d0 = y0 - mu, d1 = y1 - mu;
            float v = d0*d0 + d1*d1;
            #pragma unroll
            for (int o = 32; o >= 1; o >>= 1) v += __shfl_xor(v, o);
            float rs = rsqrtf(v*(1.0f/128.0f) + 1e-5f);
            out[(size_t)(t0 + tl)*128 + lane]      = d0*rs*ln_g[lane]    + ln_b[lane];
            out[(size_t)(t0 + tl)*128 + 64 + lane] = d1*rs*ln_g[64+lane] + ln_b[64+lane];
        }
    }
}

// ---------------------------------------------------------------------------
extern "C" void kernel_launch(void* const* d_in, const int* in_sizes, int n_in,
                              void* d_out, int out_size, void* d_ws, size_t ws_size,
                              hipStream_t stream) {
    const float* h_wq       = (const float*)d_in[0];
    const float* h_all      = (const float*)d_in[1];
    const int*   station_id = (const int*)  d_in[2];
    const float* adj        = (const float*)d_in[3];
    const float* in_proj_w  = (const float*)d_in[4];
    const float* in_proj_b  = (const float*)d_in[5];
    const float* out_w      = (const float*)d_in[6];
    const float* out_b      = (const float*)d_in[7];
    const float* gate_w     = (const float*)d_in[8];
    const float* gate_b     = (const float*)d_in[9];
    const float* ln_g       = (const float*)d_in[10];
    const float* ln_b       = (const float*)d_in[11];
    const float* alpha      = (const float*)d_in[12];
    float* out = (float*)d_out;

    fused_kernel<<<NTOK/TPB, 256, 0, stream>>>(
        h_wq, h_all, station_id, adj, in_proj_w, in_proj_b,
        out_w, out_b, gate_w, gate_b, ln_g, ln_b, alpha, out);
}